// Round 1
// baseline (486.662 us; speedup 1.0000x reference)
//
#include <hip/hip_runtime.h>
#include <math.h>

// HybridRBF: out[b] = exp(-sum_d (xn-yn)^2) + (prod_{i<8} cos(x_i-y_i))^2
// xn,yn: per-row normalize with mean, std(ddof=1)+1e-8.
// Quantum part: RY(x)RY(x)RY(-y)RY(-y)|0> -> angle 2(x-y), a0=cos(x-y).
//
// Layout: 16 lanes per row, each lane loads float4 of x and y (coalesced:
// one wave = 4 consecutive rows = 2 KiB contiguous). 5 batched butterfly
// reductions (4 stages over 16-lane groups) give raw moments.

constexpr float EPS = 1e-8f;

__global__ __launch_bounds__(256) void hybrid_rbf_kernel(
    const float* __restrict__ x, const float* __restrict__ y,
    float* __restrict__ out, int n_rows) {
    const int tid  = blockIdx.x * blockDim.x + threadIdx.x;
    const int sub  = tid & 15;        // lane within 16-lane row group
    const int row  = tid >> 4;        // one row per 16 lanes
    if (row >= n_rows) return;

    const float4 xv = ((const float4*)(x + (size_t)row * 64))[sub];
    const float4 yv = ((const float4*)(y + (size_t)row * 64))[sub];

    // per-lane partial raw moments
    float sx  = (xv.x + xv.y) + (xv.z + xv.w);
    float sy  = (yv.x + yv.y) + (yv.z + yv.w);
    float sxx = xv.x * xv.x + xv.y * xv.y + xv.z * xv.z + xv.w * xv.w;
    float syy = yv.x * yv.x + yv.y * yv.y + yv.z * yv.z + yv.w * yv.w;
    float sxy = xv.x * yv.x + xv.y * yv.y + xv.z * yv.z + xv.w * yv.w;

    // butterfly reduce across the 16-lane row group (xor masks 1,2,4,8
    // only flip low 4 lane bits -> stay within the group)
    #pragma unroll
    for (int m = 1; m < 16; m <<= 1) {
        sx  += __shfl_xor(sx,  m);
        sy  += __shfl_xor(sy,  m);
        sxx += __shfl_xor(sxx, m);
        syy += __shfl_xor(syy, m);
        sxy += __shfl_xor(sxy, m);
    }

    const float inv64 = 1.0f / 64.0f;
    const float mx = sx * inv64;
    const float my = sy * inv64;
    float vx  = sxx - sx * mx;   // sum (x-mx)^2
    float vy  = syy - sy * my;   // sum (y-my)^2
    float cxy = sxy - sx * my;   // sum (x-mx)(y-my)
    vx = fmaxf(vx, 0.0f);
    vy = fmaxf(vy, 0.0f);
    const float stdx = sqrtf(vx * (1.0f / 63.0f)) + EPS;
    const float stdy = sqrtf(vy * (1.0f / 63.0f)) + EPS;
    const float ssq = vx / (stdx * stdx) + vy / (stdy * stdy)
                    - 2.0f * cxy / (stdx * stdy);
    const float classic = __expf(-ssq);   // GAMMA = 1

    // quantum: lanes sub=0 (cols 0..3) and sub=1 (cols 4..7)
    float p = 1.0f;
    if (sub < 2) {
        p = __cosf(xv.x - yv.x) * __cosf(xv.y - yv.y)
          * __cosf(xv.z - yv.z) * __cosf(xv.w - yv.w);
    }
    const float q = p * __shfl_xor(p, 1);   // full 8-wire product on sub 0,1

    if (sub == 0) out[row] = classic + q * q;
}

extern "C" void kernel_launch(void* const* d_in, const int* in_sizes, int n_in,
                              void* d_out, int out_size, void* d_ws, size_t ws_size,
                              hipStream_t stream) {
    const float* x = (const float*)d_in[0];
    const float* y = (const float*)d_in[1];
    float* out = (float*)d_out;
    const int n_rows = in_sizes[0] / 64;          // B
    const long long total = (long long)n_rows * 16;
    const int block = 256;
    const int grid = (int)((total + block - 1) / block);
    hipLaunchKernelGGL(hybrid_rbf_kernel, dim3(grid), dim3(block), 0, stream,
                       x, y, out, n_rows);
}

// Round 3
// 469.240 us; speedup vs baseline: 1.0371x; 1.0371x over previous
//
#include <hip/hip_runtime.h>
#include <math.h>

// HybridRBF: out[b] = exp(-sum_d (xn-yn)^2) + (prod_{i<8} cos(x_i-y_i))^2
// xn,yn: per-row normalize with mean, std(ddof=1)+1e-8.
// Quantum part: RY(x)RY(x)RY(-y)RY(-y)|0> -> net angle 2(x-y), a0=cos(x-y).
//
// R2: fix nontemporal builtin — needs a native clang vector type, not
// HIP_vector_type. 8 lanes/row, each lane loads 2x float4 from x and y
// (4 independent 16B loads in flight), 3-stage butterfly over 5 moments.
// Non-temporal loads/stores: pure streaming, zero reuse.

constexpr float EPS = 1e-8f;

typedef float v4f __attribute__((ext_vector_type(4)));

__global__ __launch_bounds__(256) void hybrid_rbf_kernel(
    const float* __restrict__ x, const float* __restrict__ y,
    float* __restrict__ out, int n_rows) {
    const int tid  = blockIdx.x * blockDim.x + threadIdx.x;
    const int sub  = tid & 7;         // lane within 8-lane row group
    const int row  = tid >> 3;
    if (row >= n_rows) return;

    const v4f* xr = (const v4f*)(x + (size_t)row * 64);
    const v4f* yr = (const v4f*)(y + (size_t)row * 64);
    // first half: floats [4*sub, 4*sub+4); second half: [32+4*sub, ...)
    const v4f xa = __builtin_nontemporal_load(xr + sub);
    const v4f xb = __builtin_nontemporal_load(xr + sub + 8);
    const v4f ya = __builtin_nontemporal_load(yr + sub);
    const v4f yb = __builtin_nontemporal_load(yr + sub + 8);

    // per-lane partial raw moments over 8 elements
    float sx  = ((xa.x + xa.y) + (xa.z + xa.w)) + ((xb.x + xb.y) + (xb.z + xb.w));
    float sy  = ((ya.x + ya.y) + (ya.z + ya.w)) + ((yb.x + yb.y) + (yb.z + yb.w));
    float sxx = xa.x*xa.x + xa.y*xa.y + xa.z*xa.z + xa.w*xa.w
              + xb.x*xb.x + xb.y*xb.y + xb.z*xb.z + xb.w*xb.w;
    float syy = ya.x*ya.x + ya.y*ya.y + ya.z*ya.z + ya.w*ya.w
              + yb.x*yb.x + yb.y*yb.y + yb.z*yb.z + yb.w*yb.w;
    float sxy = xa.x*ya.x + xa.y*ya.y + xa.z*ya.z + xa.w*ya.w
              + xb.x*yb.x + xb.y*yb.y + xb.z*yb.z + xb.w*yb.w;

    // butterfly reduce across the 8-lane row group (masks 1,2,4 stay in-group)
    #pragma unroll
    for (int m = 1; m < 8; m <<= 1) {
        sx  += __shfl_xor(sx,  m);
        sy  += __shfl_xor(sy,  m);
        sxx += __shfl_xor(sxx, m);
        syy += __shfl_xor(syy, m);
        sxy += __shfl_xor(sxy, m);
    }

    const float inv64 = 1.0f / 64.0f;
    const float mx = sx * inv64;
    const float my = sy * inv64;
    float vx  = sxx - sx * mx;   // sum (x-mx)^2
    float vy  = syy - sy * my;   // sum (y-my)^2
    float cxy = sxy - sx * my;   // sum (x-mx)(y-my)
    vx = fmaxf(vx, 0.0f);
    vy = fmaxf(vy, 0.0f);
    const float stdx = sqrtf(vx * (1.0f / 63.0f)) + EPS;
    const float stdy = sqrtf(vy * (1.0f / 63.0f)) + EPS;
    const float ssq = vx / (stdx * stdx) + vy / (stdy * stdy)
                    - 2.0f * cxy / (stdx * stdy);
    const float classic = __expf(-ssq);   // GAMMA = 1

    // quantum: cols 0..7 live in xa/ya of sub=0 (cols 0..3) and sub=1 (4..7)
    float p = 1.0f;
    if (sub < 2) {
        p = __cosf(xa.x - ya.x) * __cosf(xa.y - ya.y)
          * __cosf(xa.z - ya.z) * __cosf(xa.w - ya.w);
    }
    const float q = p * __shfl_xor(p, 1);   // full 8-wire product on sub 0,1

    if (sub == 0) {
        __builtin_nontemporal_store(classic + q * q, out + row);
    }
}

extern "C" void kernel_launch(void* const* d_in, const int* in_sizes, int n_in,
                              void* d_out, int out_size, void* d_ws, size_t ws_size,
                              hipStream_t stream) {
    const float* x = (const float*)d_in[0];
    const float* y = (const float*)d_in[1];
    float* out = (float*)d_out;
    const int n_rows = in_sizes[0] / 64;          // B = 1048576
    const long long total = (long long)n_rows * 8;
    const int block = 256;
    const int grid = (int)((total + block - 1) / block);
    hipLaunchKernelGGL(hybrid_rbf_kernel, dim3(grid), dim3(block), 0, stream,
                       x, y, out, n_rows);
}